// Round 4
// baseline (304.274 us; speedup 1.0000x reference)
//
#include <hip/hip_runtime.h>
#include <cstdint>
#include <cstddef>

#define NT 256
#define LOG2E 1.4426950408889634f

typedef float v2f __attribute__((ext_vector_type(2)));
typedef float v4f __attribute__((ext_vector_type(4)));

#if defined(__has_builtin)
#  if __has_builtin(__builtin_amdgcn_exp2f)
#    define EXP2F(x) __builtin_amdgcn_exp2f(x)
#  else
#    define EXP2F(x) exp2f(x)
#  endif
#else
#  define EXP2F(x) exp2f(x)
#endif

// ---------------- shared-memory layout (float offsets) ----------------
enum {
  OFF_EEGB = 0,       // 8
  OFF_PSAW = 8,       // 16
  OFF_PSAB = 24,      // 8
  OFF_LOCW = 32,      // 24
  OFF_LOCB = 56,      // 8
  OFF_TGTW = 64,      // 8
  OFF_TGTB = 72,      // 8
  OFF_NG   = 80,      // 8
  OFF_NB   = 88,      // 8
  OFF_CINW = 96,      // 192 (q-rows pre-scaled by log2e)
  OFF_CINB = 288,     // 24
  OFF_COUTW= 312,     // 64
  OFF_COUTB= 376,     // 8
  OFF_SINW = 384,     // 192
  OFF_SINB = 576,     // 24
  OFF_SOUTW= 600,     // 64
  OFF_SOUTB= 664,     // 8
  OFF_OINW = 672,     // 192
  OFF_OINB = 864,     // 24
  OFF_OOUTW= 888,     // 64
  OFF_OOUTB= 952,     // 8
  OFF_FC1B = 960,     // 90 -> 1050
  OFF_PE30 = 1052,    // 8
  OFF_PE32 = 1060,    // 8 -> 1068
  OFF_Ebuf = 1068,    // 240
  OFF_Pbuf = 1308,    // 256
  OFF_Sbuf = 1564,    // 256
  OFF_Abuf = 1820,    // 256
  OFF_Lbuf = 2076,    // 256
  OFF_Tbuf = 2332,    // 256
  OFF_CAT  = 2588,    // 1008 -> 3596
  OFF_QP   = 3596,    // 256 (ov exchange; final raw output for fc1)
  OFF_KS   = 3852,    // 8*68 = 544 (k, h-major, padded stride 68)
  OFF_VS   = 4396,    // 544
  OFF_FCO  = 4940,    // 90 -> 5030
  SM_TOTAL = 5032,    // 20128 B -> 8 blocks/CU
  OFF_EEGW = OFF_KS,  // 640 floats, aliased: dead before first kv-proj
};

struct MhaDesc { int Lq, Lk, kstart, qoff, kvoff, wset, dst1, dst2, flags; };
// flags: bit0 = first pass (project q, zero accumulators); bit1 = last pass (finalize)

#define EB 0
#define PB 30
#define AB 62
#define SB 94
static __device__ const MhaDesc g_desc[20] = {
  {30, 32, 0, OFF_Ebuf, OFF_Pbuf, 0, EB, -1, 3},   // cross(e,p)
  {30, 32, 0, OFF_Ebuf, OFF_Abuf, 0, EB, -1, 3},   // cross(e,a)
  {30, 32, 0, OFF_Ebuf, OFF_Lbuf, 0, EB, -1, 3},   // cross(e,l)
  {30, 30, 0, OFF_Ebuf, OFF_Ebuf, 1, EB, -1, 3},   // selfa(e)
  {30, 32, 0, OFF_Ebuf, OFF_Sbuf, 0, EB, -1, 3},   // cross(e,s)
  {32, 30, 0, OFF_Pbuf, OFF_Ebuf, 0, PB, -1, 3},   // cross(p,e)
  {32, 32, 0, OFF_Pbuf, OFF_Abuf, 0, PB, -1, 3},   // cross(p,a)
  {32, 32, 0, OFF_Pbuf, OFF_Lbuf, 0, PB, -1, 3},   // cross(p,l)
  {32, 32, 0, OFF_Pbuf, OFF_Pbuf, 1, PB, -1, 3},   // selfa(p)
  {32, 32, 0, OFF_Pbuf, OFF_Sbuf, 0, PB, -1, 3},   // cross(p,s)
  {32, 30, 0, OFF_Sbuf, OFF_Ebuf, 0, SB, -1, 3},   // cross(s,e)
  {32, 32, 0, OFF_Sbuf, OFF_Pbuf, 0, SB, -1, 3},   // cross(s,p)
  {32, 32, 0, OFF_Sbuf, OFF_Abuf, 0, SB, -1, 3},   // cross(s,a)
  {32, 32, 0, OFF_Sbuf, OFF_Lbuf, 0, SB, AB, 3},   // cross(s,l) -> speech AND action
  {32, 30, 0, OFF_Abuf, OFF_Ebuf, 0, AB, -1, 3},   // cross(a,e)
  {32, 32, 0, OFF_Abuf, OFF_Pbuf, 0, AB, -1, 3},   // cross(a,p)
  {32, 32, 0, OFF_Abuf, OFF_Abuf, 1, AB, -1, 3},   // selfa(a)
  {32, 32, 0, OFF_Abuf, OFF_Sbuf, 0, AB, -1, 3},   // cross(a,s)
  {32, 64, 0,  OFF_Tbuf, OFF_CAT, 2, -1, -1, 1},   // final MHA pass 1 (k 0..63)
  {32, 62, 64, OFF_Tbuf, OFF_CAT, 2, -1, -1, 2},   // final MHA pass 2 (k 64..125)
};

__device__ __forceinline__ float grp8_sum(float v) {
  v += __shfl_xor(v, 1);
  v += __shfl_xor(v, 2);
  v += __shfl_xor(v, 4);
  return v;
}

// 8-elem dot product via packed f32 ops
__device__ __forceinline__ float dot8(const float* __restrict__ x,
                                      const float* __restrict__ w, float bias) {
  v4f xa = *(const v4f*)x, xb = *(const v4f*)(x + 4);
  v4f wa = *(const v4f*)w, wb = *(const v4f*)(w + 4);
  v4f p = xa * wa;
  p += xb * wb;
  v2f q = p.xy + p.zw;
  return bias + q.x + q.y;
}

// fully-unrolled packed attention accumulation over LK keys
template<int LK>
__device__ __forceinline__ void attn_accum(float qq, const float* __restrict__ Kp,
                                           const float* __restrict__ Vp,
                                           v4f& l4, v4f& A4) {
  constexpr int N4 = LK >> 2;
  #pragma unroll
  for (int k4 = 0; k4 < N4; k4++) {
    v4f kk = *(const v4f*)(Kp + 4 * k4);
    v4f vv = *(const v4f*)(Vp + 4 * k4);
    v4f sc = kk * qq;                       // 2x v_pk_mul_f32
    v4f ee = { EXP2F(sc.x), EXP2F(sc.y), EXP2F(sc.z), EXP2F(sc.w) };
    l4 += ee;                               // 2x v_pk_add_f32
    A4 += ee * vv;                          // 2x v_pk_fma_f32
  }
  if constexpr ((LK & 3) != 0) {            // LK%4 == 2 in all our shapes
    v2f kk = *(const v2f*)(Kp + 4 * N4);
    v2f vv = *(const v2f*)(Vp + 4 * N4);
    v2f sc = kk * qq;
    v2f ee = { EXP2F(sc.x), EXP2F(sc.y) };
    l4.xy = l4.xy + ee;
    A4.xy = A4.xy + ee * vv;
  }
}

__global__ __launch_bounds__(NT, 8) void cmt_kernel(
    const float* __restrict__ eeg, const float* __restrict__ pupil,
    const float* __restrict__ speech, const float* __restrict__ action,
    const float* __restrict__ location, const float* __restrict__ tgt,
    const float* __restrict__ eeg_w, const float* __restrict__ eeg_b,
    const float* __restrict__ psa_w, const float* __restrict__ psa_b,
    const float* __restrict__ loc_w, const float* __restrict__ loc_b,
    const float* __restrict__ tgt_w, const float* __restrict__ tgt_b,
    const float* __restrict__ ng, const float* __restrict__ nb,
    const float* __restrict__ cin_w, const float* __restrict__ cin_b,
    const float* __restrict__ cout_w, const float* __restrict__ cout_b,
    const float* __restrict__ sin_w, const float* __restrict__ sin_b,
    const float* __restrict__ sout_w, const float* __restrict__ sout_b,
    const float* __restrict__ oin_w, const float* __restrict__ oin_b,
    const float* __restrict__ oout_w, const float* __restrict__ oout_b,
    const float* __restrict__ fc1_w, const float* __restrict__ fc1_b,
    float* __restrict__ out)
{
  __shared__ __align__(16) float sm[SM_TOTAL];
  const int tid = threadIdx.x;
  const int b = blockIdx.x;

#define CP(off, p, n) for (int i = tid; i < (n); i += NT) sm[(off)+i] = (p)[i]
#define CPQ(off, p, n, nq) for (int i = tid; i < (n); i += NT) sm[(off)+i] = (p)[i] * ((i < (nq)) ? LOG2E : 1.0f)

  // ---------- phase 0: stage weights ----------
  for (int i = tid; i < 640; i += NT) sm[OFF_EEGW + i] = eeg_w[(i & 7) * 80 + (i >> 3)];
  CP(OFF_EEGB, eeg_b, 8);
  CP(OFF_PSAW, psa_w, 16);   CP(OFF_PSAB, psa_b, 8);
  CP(OFF_LOCW, loc_w, 24);   CP(OFF_LOCB, loc_b, 8);
  CP(OFF_TGTW, tgt_w, 8);    CP(OFF_TGTB, tgt_b, 8);
  CP(OFF_NG, ng, 8);         CP(OFF_NB, nb, 8);
  CPQ(OFF_CINW, cin_w, 192, 64);  CPQ(OFF_CINB, cin_b, 24, 8);
  CP(OFF_COUTW, cout_w, 64); CP(OFF_COUTB, cout_b, 8);
  CPQ(OFF_SINW, sin_w, 192, 64);  CPQ(OFF_SINB, sin_b, 24, 8);
  CP(OFF_SOUTW, sout_w, 64); CP(OFF_SOUTB, sout_b, 8);
  CPQ(OFF_OINW, oin_w, 192, 64);  CPQ(OFF_OINB, oin_b, 24, 8);
  CP(OFF_OOUTW, oout_w, 64); CP(OFF_OOUTB, oout_b, 8);
  CP(OFF_FC1B, fc1_b, 90);
  for (int i = tid; i < 1008; i += NT) sm[OFF_CAT + i] = 0.f;
  if (tid < 16) {
    const float divs[4] = {1.f, 0.1f, 0.01f, 0.001f};
    float pos = (tid < 8) ? 30.f : 32.f;
    int e = tid & 7;
    float x = pos * divs[e >> 1];
    float v = (e & 1) ? cosf(x) : sinf(x);
    sm[((tid < 8) ? OFF_PE30 : OFF_PE32) + e] = v;
  }
  __syncthreads();

  // ---------- phase 1: convs + positional encoding ----------
  if (tid < 240) {  // eeg conv2d -> e[30][8]
    int w = tid >> 3, o = tid & 7;
    const float* ep = eeg + (size_t)b * 4720 + 4 * w;
    const float* wt = sm + OFF_EEGW + o;
    float acc = sm[OFF_EEGB + o];
    #pragma unroll
    for (int i = 0; i < 2; i++)
      #pragma unroll
      for (int kh = 0; kh < 20; kh++) {
        float2 x = *(const float2*)(ep + i * 2360 + kh * 118);
        int ik = i * 20 + kh;
        acc = fmaf(x.x, wt[ik * 16], fmaf(x.y, wt[ik * 16 + 8], acc));
      }
    sm[OFF_Ebuf + w * 8 + o] = acc + sm[OFF_PE30 + o];
  }
  {  // conv1d k=1 pad=1 -> length-32 sequences, + pe32
    int t = tid >> 3, o = tid & 7;
    bool inb = (t >= 1 && t <= 30);
    int ti = t - 1;
    float pe = sm[OFF_PE32 + o];
    float w0 = sm[OFF_PSAW + 2 * o], w1 = sm[OFF_PSAW + 2 * o + 1];
    float pb = sm[OFF_PSAB + o];
    float vp = pb, vs = pb, va = pb;
    float vl = sm[OFF_LOCB + o], vt = sm[OFF_TGTB + o];
    if (inb) {
      const float* pp = pupil    + (size_t)b * 60 + ti;
      const float* sp = speech   + (size_t)b * 60 + ti;
      const float* ap = action   + (size_t)b * 60 + ti;
      const float* lp = location + (size_t)b * 90 + ti;
      vp = fmaf(pp[0], w0, fmaf(pp[30], w1, vp));
      vs = fmaf(sp[0], w0, fmaf(sp[30], w1, vs));
      va = fmaf(ap[0], w0, fmaf(ap[30], w1, va));
      vl = fmaf(lp[0],  sm[OFF_LOCW + 3 * o],     vl);
      vl = fmaf(lp[30], sm[OFF_LOCW + 3 * o + 1], vl);
      vl = fmaf(lp[60], sm[OFF_LOCW + 3 * o + 2], vl);
      vt = fmaf(tgt[(size_t)b * 30 + ti], sm[OFF_TGTW + o], vt);
    }
    sm[OFF_Pbuf + tid] = vp + pe;
    sm[OFF_Sbuf + tid] = vs + pe;
    sm[OFF_Abuf + tid] = va + pe;
    sm[OFF_Lbuf + tid] = vl + pe;
    sm[OFF_Tbuf + tid] = vt + pe;
  }
  __syncthreads();

  // ---------- phase 2: 19 MHAs (final one in 2 accumulate passes) ----------
  float q_reg = 0.f;
  v4f l4 = {0.f, 0.f, 0.f, 0.f}, A4 = {0.f, 0.f, 0.f, 0.f};
  for (int mi = 0; mi < 20; mi++) {
    const MhaDesc d = g_desc[mi];
    int winO, binO, woutO, boutO;
    if (d.wset == 0)      { winO = OFF_CINW; binO = OFF_CINB; woutO = OFF_COUTW; boutO = OFF_COUTB; }
    else if (d.wset == 1) { winO = OFF_SINW; binO = OFF_SINB; woutO = OFF_SOUTW; boutO = OFF_SOUTB; }
    else                  { winO = OFF_OINW; binO = OFF_OINB; woutO = OFF_OOUTW; boutO = OFF_OOUTB; }

    // q projection -> register (weights pre-scaled by log2e)
    if ((d.flags & 1) && tid < d.Lq * 8) {
      int r = tid >> 3, h = tid & 7;
      q_reg = dot8(sm + d.qoff + r * 8, sm + winO + h * 8, sm[binO + h]);
    }
    // k,v projection into h-major padded arrays
    for (int idx = tid; idx < d.Lk * 8; idx += NT) {
      int r = idx >> 3, h = idx & 7;
      const float* x = sm + d.kvoff + (d.kstart + r) * 8;
      v4f xa = *(const v4f*)x, xb = *(const v4f*)(x + 4);
      const float* wk = sm + winO + 64 + h * 8;
      const float* wv = sm + winO + 128 + h * 8;
      v4f pk = xa * *(const v4f*)wk;  pk += xb * *(const v4f*)(wk + 4);
      v4f pv = xa * *(const v4f*)wv;  pv += xb * *(const v4f*)(wv + 4);
      v2f hk = pk.xy + pk.zw, hv = pv.xy + pv.zw;
      sm[OFF_KS + h * 68 + r] = sm[binO + 8 + h]  + hk.x + hk.y;
      sm[OFF_VS + h * 68 + r] = sm[binO + 16 + h] + hv.x + hv.y;
    }
    __syncthreads();

    // attention (no max pass: softmax shift-invariant, scores bounded)
    if (tid < d.Lq * 8) {
      int e = tid & 7;
      if (d.flags & 1) { l4 = (v4f){0.f,0.f,0.f,0.f}; A4 = (v4f){0.f,0.f,0.f,0.f}; }
      const float* Kp = sm + OFF_KS + e * 68;
      const float* Vp = sm + OFF_VS + e * 68;
      switch (d.Lk) {
        case 32: attn_accum<32>(q_reg, Kp, Vp, l4, A4); break;
        case 30: attn_accum<30>(q_reg, Kp, Vp, l4, A4); break;
        case 64: attn_accum<64>(q_reg, Kp, Vp, l4, A4); break;
        case 62: attn_accum<62>(q_reg, Kp, Vp, l4, A4); break;
        default: __builtin_unreachable();
      }
      if (d.flags & 2) {
        v2f lp = l4.xy + l4.zw, ap = A4.xy + A4.zw;
        float ov = (ap.x + ap.y) * __builtin_amdgcn_rcpf(lp.x + lp.y);
        // 8-group exchange through LDS (same wave -> no barrier needed)
        sm[OFF_QP + tid] = ov;
        int gb = tid & ~7;
        float a = dot8(sm + OFF_QP + gb, sm + woutO + e * 8, sm[boutO + e]);
        if (d.dst1 >= 0) {
          int qi = tid >> 3;
          float mu = grp8_sum(a) * 0.125f;
          float dd = a - mu;
          float var = grp8_sum(dd * dd) * 0.125f;
          float nv = fmaf(dd * rsqrtf(var + 1e-5f), sm[OFF_NG + e], sm[OFF_NB + e]);
          sm[OFF_CAT + (d.dst1 + qi) * 8 + e] += nv;
          if (d.dst2 >= 0) sm[OFF_CAT + (d.dst2 + qi) * 8 + e] += nv;
        } else {
          sm[OFF_QP + tid] = a;  // final MHA raw output (32,8) for fc1
        }
      }
    }
    __syncthreads();
  }

  // ---------- phase 3: fc1 (2 threads per output) + channel softmax ----------
  if (tid < 180) {
    int j = tid >> 1, p = tid & 1;
    const v4f* w4 = (const v4f*)(fc1_w + j * 256);
    const v4f* o4 = (const v4f*)(sm + OFF_QP);
    v4f acc4 = {0.f, 0.f, 0.f, 0.f};
    #pragma unroll 8
    for (int c = p; c < 64; c += 2) acc4 += o4[c] * w4[c];
    v2f a2 = acc4.xy + acc4.zw;
    float acc = a2.x + a2.y;
    acc += __shfl_xor(acc, 1);
    if (p == 0) sm[OFF_FCO + j] = acc + sm[OFF_FC1B + j];
  }
  __syncthreads();
  if (tid < 30) {
    float x0 = sm[OFF_FCO + 3 * tid], x1 = sm[OFF_FCO + 3 * tid + 1], x2 = sm[OFF_FCO + 3 * tid + 2];
    float m = fmaxf(x0, fmaxf(x1, x2));
    float e0 = __expf(x0 - m), e1 = __expf(x1 - m), e2 = __expf(x2 - m);
    float inv = __builtin_amdgcn_rcpf(e0 + e1 + e2);
    float* op = out + (size_t)b * 90;
    op[tid]      = e0 * inv;
    op[30 + tid] = e1 * inv;
    op[60 + tid] = e2 * inv;
  }
#undef CP
#undef CPQ
}

extern "C" void kernel_launch(void* const* d_in, const int* in_sizes, int n_in,
                              void* d_out, int out_size, void* d_ws, size_t ws_size,
                              hipStream_t stream) {
  (void)n_in; (void)out_size; (void)d_ws; (void)ws_size;
  int B = in_sizes[0] / 4720;  // eeg = (B,2,20,118)
  cmt_kernel<<<B, NT, 0, stream>>>(
      (const float*)d_in[0],  (const float*)d_in[1],  (const float*)d_in[2],
      (const float*)d_in[3],  (const float*)d_in[4],  (const float*)d_in[5],
      (const float*)d_in[6],  (const float*)d_in[7],  (const float*)d_in[8],
      (const float*)d_in[9],  (const float*)d_in[10], (const float*)d_in[11],
      (const float*)d_in[12], (const float*)d_in[13], (const float*)d_in[14],
      (const float*)d_in[15], (const float*)d_in[16], (const float*)d_in[17],
      (const float*)d_in[18], (const float*)d_in[19], (const float*)d_in[20],
      (const float*)d_in[21], (const float*)d_in[22], (const float*)d_in[23],
      (const float*)d_in[24], (const float*)d_in[25], (const float*)d_in[26],
      (const float*)d_in[27], (const float*)d_in[28], (const float*)d_in[29],
      (float*)d_out);
}